// Round 6
// baseline (1052.244 us; speedup 1.0000x reference)
//
#include <hip/hip_runtime.h>

// SpikingMultiHeadAttention — B=2, S=2048, D=1024, H=16, hd=64, fp32 I/O.
// Round 9: attn_mfma processes 64 keys per barrier (two 32-key halves,
// no barrier between — Ps rows are wave-private + lgkm-ordered): halves the
// syncthreads count and gives the scheduler two independent half-chains to
// overlap. K dbuf-staged 64 keys/tile via global_load_lds w/ pre-swizzled
// source (r8 mechanism, HW-validated). Both halves' V loads issue BEFORE the
// stage so PV's vmcnt wait keeps stage loads in flight (in-order vmcnt).
// proj_out: occupancy 2->4 blocks/CU (16-row waves, grid 64x16, lb(256,4)).
// Numerics bit-identical to r8 (same bf16 words, same MFMA order): absmax 1.75.
// MFMA 16x16x32 bf16 layouts (HW-verified):
//   A-frag: lane holds A[m=lane&15][k=(lane>>4)*8+j], j=0..7
//   B-frag: lane holds Bt[n=lane&15][k=(lane>>4)*8+j]
//   C/D:    lane,reg r -> row m=(lane>>4)*4+r, col n=lane&15

#define SEQ 2048
#define DIM 1024
#define NH 16
#define HD 64
#define BATCH 2
#define MROWS (BATCH * SEQ)   // 4096
#define BHT (BATCH * NH)      // 32

typedef __attribute__((ext_vector_type(8))) short short8;
typedef __attribute__((ext_vector_type(4))) float f4;
typedef unsigned short ushort;

__device__ __forceinline__ f4 mfma16(short8 a, short8 b, f4 c) {
    return __builtin_amdgcn_mfma_f32_16x16x32_bf16(a, b, c, 0, 0, 0);
}
__device__ __forceinline__ ushort rne16(float x) {
    union { float f; unsigned u; } a; a.f = x;
    return (ushort)((a.u + 0x7fffu + ((a.u >> 16) & 1u)) >> 16);
}
// x ~= hi + lo: hi = truncate-to-bf16(x), lo = rne-bf16(x - hi)
__device__ __forceinline__ void split2(float x, ushort& h, ushort& l) {
    union { float f; unsigned u; } a; a.f = x;
    unsigned hu = a.u & 0xffff0000u;
    h = (ushort)(hu >> 16);
    union { unsigned u; float f; } hb; hb.u = hu;
    l = rne16(x - hb.f);
}
__device__ __forceinline__ short8 ld8(const ushort* p) { return *(const short8*)p; }

// async global->LDS, 16B per lane; LDS dest wave-uniform base, HW writes
// lane i at base + i*16. Global addr is per-lane.
__device__ __forceinline__ void gll16(const ushort* g, ushort* l) {
    __builtin_amdgcn_global_load_lds((const __attribute__((address_space(1))) void*)g,
                                     (__attribute__((address_space(3))) void*)l, 16, 0, 0);
}

// ---------- fused weight conversion: 4 jobs on grid.y ----------
__global__ __launch_bounds__(256) void wconv(const float* __restrict__ Wq,
                                             const float* __restrict__ Wk,
                                             const float* __restrict__ Wv,
                                             const float* __restrict__ Wo,
                                             ushort* __restrict__ Wqh, ushort* __restrict__ Wql,
                                             ushort* __restrict__ Wkh, ushort* __restrict__ Wkl,
                                             ushort* __restrict__ Wvb, ushort* __restrict__ Wob) {
    int i = (blockIdx.x * 256 + threadIdx.x) * 4;
    int job = blockIdx.y;
    const float* src = job == 0 ? Wq : job == 1 ? Wk : job == 2 ? Wv : Wo;
    float4 w = *(const float4*)&src[i];
    float xs[4] = {w.x, w.y, w.z, w.w};
    if (job < 2) {
        ushort h[4], l[4];
#pragma unroll
        for (int j = 0; j < 4; ++j) split2(xs[j], h[j], l[j]);
        ushort* ph = job ? Wkh : Wqh;
        ushort* pl = job ? Wkl : Wql;
        *(short4*)&ph[i] = make_short4(h[0], h[1], h[2], h[3]);
        *(short4*)&pl[i] = make_short4(l[0], l[1], l[2], l[3]);
    } else {
        ushort* po = job == 2 ? Wvb : Wob;
        *(short4*)&po[i] = make_short4(rne16(xs[0]), rne16(xs[1]), rne16(xs[2]), rne16(xs[3]));
    }
}

// ---------- fused q/k/v projection (grid.z selects), pipelined loads ----------
template <int B>
__device__ __forceinline__ void ld_qk(const float* __restrict__ X, const ushort* __restrict__ Wh,
                                      const ushort* __restrict__ Wl, int m0, int n0, int la, int qd,
                                      int k0, float4 (&xA)[2][2][2], short8 (&wH)[2][4],
                                      short8 (&wL)[2][4]) {
#pragma unroll
    for (int ms = 0; ms < 2; ++ms) {
        const float* ap = &X[(size_t)(m0 + ms * 16 + la) * DIM + k0 + qd * 8];
        xA[B][ms][0] = *(const float4*)ap;
        xA[B][ms][1] = *(const float4*)(ap + 4);
    }
#pragma unroll
    for (int ns = 0; ns < 4; ++ns) {
        size_t wi = (size_t)(n0 + ns * 16 + la) * DIM + k0 + qd * 8;
        wH[B][ns] = ld8(&Wh[wi]);
        wL[B][ns] = ld8(&Wl[wi]);
    }
}

template <int B>
__device__ __forceinline__ void fma_qk(float4 (&xA)[2][2][2], short8 (&wH)[2][4],
                                       short8 (&wL)[2][4], f4 (&acc)[2][4]) {
    short8 ahi[2], alo[2];
#pragma unroll
    for (int ms = 0; ms < 2; ++ms) {
        float xs[8] = {xA[B][ms][0].x, xA[B][ms][0].y, xA[B][ms][0].z, xA[B][ms][0].w,
                       xA[B][ms][1].x, xA[B][ms][1].y, xA[B][ms][1].z, xA[B][ms][1].w};
#pragma unroll
        for (int j = 0; j < 8; ++j) {
            ushort h, l;
            split2(xs[j], h, l);
            ahi[ms][j] = (short)h;
            alo[ms][j] = (short)l;
        }
    }
#pragma unroll
    for (int ns = 0; ns < 4; ++ns)
#pragma unroll
        for (int ms = 0; ms < 2; ++ms) {
            acc[ms][ns] = mfma16(alo[ms], wH[B][ns], acc[ms][ns]);
            acc[ms][ns] = mfma16(ahi[ms], wL[B][ns], acc[ms][ns]);
            acc[ms][ns] = mfma16(ahi[ms], wH[B][ns], acc[ms][ns]);
        }
}

template <int B>
__device__ __forceinline__ void ld_v(const float* __restrict__ X, const ushort* __restrict__ Wb,
                                     int m0, int n0, int la, int qd, int k0,
                                     float4 (&xA)[2][2][2], short8 (&wH)[2][4]) {
#pragma unroll
    for (int ms = 0; ms < 2; ++ms) {
        const float* ap = &X[(size_t)(m0 + ms * 16 + la) * DIM + k0 + qd * 8];
        xA[B][ms][0] = *(const float4*)ap;
        xA[B][ms][1] = *(const float4*)(ap + 4);
    }
#pragma unroll
    for (int ns = 0; ns < 4; ++ns)
        wH[B][ns] = ld8(&Wb[(size_t)(n0 + ns * 16 + la) * DIM + k0 + qd * 8]);
}

template <int B>
__device__ __forceinline__ void fma_v(float4 (&xA)[2][2][2], short8 (&wH)[2][4], f4 (&acc)[2][4]) {
    short8 a[2];
#pragma unroll
    for (int ms = 0; ms < 2; ++ms) {
        float xs[8] = {xA[B][ms][0].x, xA[B][ms][0].y, xA[B][ms][0].z, xA[B][ms][0].w,
                       xA[B][ms][1].x, xA[B][ms][1].y, xA[B][ms][1].z, xA[B][ms][1].w};
#pragma unroll
        for (int j = 0; j < 8; ++j) a[ms][j] = (short)rne16(xs[j]);
    }
#pragma unroll
    for (int ns = 0; ns < 4; ++ns)
#pragma unroll
        for (int ms = 0; ms < 2; ++ms) acc[ms][ns] = mfma16(a[ms], wH[B][ns], acc[ms][ns]);
}

__global__ __launch_bounds__(256, 2) void proj_qkv(
    const float* __restrict__ query, const float* __restrict__ key, const float* __restrict__ value,
    const ushort* __restrict__ Wqh, const ushort* __restrict__ Wql,
    const ushort* __restrict__ Wkh, const ushort* __restrict__ Wkl,
    const ushort* __restrict__ Wvb,
    const float* __restrict__ bq, const float* __restrict__ bk, const float* __restrict__ bv,
    ushort* __restrict__ Qhi, ushort* __restrict__ Qlo,
    ushort* __restrict__ Khi, ushort* __restrict__ Klo, ushort* __restrict__ Vt) {
    const int z = blockIdx.z;
    const int t = threadIdx.x, wave = t >> 6, lane = t & 63;
    const int la = lane & 15, qd = lane >> 4;
    const int m0 = blockIdx.x * 128 + wave * 32;
    const int n0 = blockIdx.y * 64;

    float4 xA[2][2][2];
    short8 wH[2][4], wL[2][4];
    f4 acc[2][4] = {};

    if (z < 2) {
        const float* X = z ? key : query;
        const ushort* Wh = z ? Wkh : Wqh;
        const ushort* Wl = z ? Wkl : Wql;
        ld_qk<0>(X, Wh, Wl, m0, n0, la, qd, 0, xA, wH, wL);
        for (int k0 = 0; k0 < DIM; k0 += 64) {
            ld_qk<1>(X, Wh, Wl, m0, n0, la, qd, k0 + 32, xA, wH, wL);
            fma_qk<0>(xA, wH, wL, acc);
            ld_qk<0>(X, Wh, Wl, m0, n0, la, qd, (k0 + 64) & (DIM - 1), xA, wH, wL);
            fma_qk<1>(xA, wH, wL, acc);
        }
        const float* bias = z ? bk : bq;
        ushort* Oh = z ? Khi : Qhi;
        ushort* Ol = z ? Klo : Qlo;
#pragma unroll
        for (int ns = 0; ns < 4; ++ns) {
            int n = n0 + ns * 16 + la;
            float bvv = bias[n];
            int h = n >> 6, d = n & 63;
#pragma unroll
            for (int ms = 0; ms < 2; ++ms)
#pragma unroll
                for (int r = 0; r < 4; ++r) {
                    int m = m0 + ms * 16 + qd * 4 + r;
                    int b = m >> 11, s = m & 2047;
                    ushort hh, ll;
                    split2(acc[ms][ns][r] + bvv, hh, ll);
                    size_t o = ((size_t)(b * NH + h) * SEQ + s) * HD + d;
                    __builtin_nontemporal_store(hh, &Oh[o]);
                    __builtin_nontemporal_store(ll, &Ol[o]);
                }
        }
    } else {
        __shared__ ushort Ts[4][64][40];  // per-wave private [wave][d][m], 16B-aligned rows
        ld_v<0>(value, Wvb, m0, n0, la, qd, 0, xA, wH);
        for (int k0 = 0; k0 < DIM; k0 += 64) {
            ld_v<1>(value, Wvb, m0, n0, la, qd, k0 + 32, xA, wH);
            fma_v<0>(xA, wH, acc);
            ld_v<0>(value, Wvb, m0, n0, la, qd, (k0 + 64) & (DIM - 1), xA, wH);
            fma_v<1>(xA, wH, acc);
        }
#pragma unroll
        for (int ns = 0; ns < 4; ++ns) {
            float bvv = bv[n0 + ns * 16 + la];
#pragma unroll
            for (int ms = 0; ms < 2; ++ms)
#pragma unroll
                for (int r = 0; r < 4; ++r)
                    Ts[wave][ns * 16 + la][ms * 16 + qd * 4 + r] = rne16(acc[ms][ns][r] + bvv);
        }
        // same-wave LDS round-trip (lgkmcnt-ordered, wave-private region)
        int b = m0 >> 11, s0 = m0 & 2047, h = n0 >> 6;
        size_t vbase = (size_t)(b * NH + h) * HD * SEQ;
#pragma unroll
        for (int it = 0; it < 4; ++it) {
            int d = it * 16 + (lane >> 2), sc = (lane & 3) * 8;
            short8 v0 = *(const short8*)&Ts[wave][d][sc];
            __builtin_nontemporal_store(v0, (short8*)&Vt[vbase + (size_t)d * SEQ + s0 + sc]);
        }
    }
}

// ---------- fused attention: LDS-staged K (dbuf, swizzled), 64-key tiles ----
// Grid 32 (bh) x 32 (q-blocks of 64). 4 waves/block share the K tile.
// LDS: kb[2][2][64][64] = 32 KiB + Ps 5 KiB = 37 KiB -> 4 blocks/CU.
// Two 32-key halves per barrier; Ps rows wave-private (lgkm-ordered).
__global__ __launch_bounds__(256, 4) void attn_mfma(
    const ushort* __restrict__ Qhi, const ushort* __restrict__ Qlo,
    const ushort* __restrict__ Khi, const ushort* __restrict__ Klo,
    const ushort* __restrict__ Vt, float* __restrict__ attn, ushort* __restrict__ ctxb) {
    __shared__ ushort kb[2][2][64][64];  // [buf][hl][key][halfword], chunk-swizzled content
    __shared__ ushort Ps[64][40];        // 4 waves x 16 wave-private rows
    const int t = threadIdx.x, wave = t >> 6, lane = t & 63;
    const int la = lane & 15, qd = lane >> 4;
    const int bh = blockIdx.x;
    const int q0 = blockIdx.y * 64 + wave * 16;

    short8 qhi[2], qlo[2];
#pragma unroll
    for (int ks = 0; ks < 2; ++ks) {
        size_t qi = ((size_t)bh * SEQ + q0 + la) * HD + ks * 32 + qd * 8;
        qhi[ks] = ld8(&Qhi[qi]);
        qlo[ks] = ld8(&Qlo[qi]);
    }

    // staging geometry: wave w stages keys [w*16, w*16+16) of the 64-key tile
    // in two 8-key groups. lane l -> key (group*8)+(l>>3), LDS chunk (l&7).
    // LDS slot [key][j] holds GLOBAL chunk j^(key&7) (involution), so the read
    // applies the same XOR. key&7 == l>>3 for both groups.
    const int skey = wave * 16 + (lane >> 3);
    const int schunk = (lane & 7) ^ (lane >> 3);
    const size_t sg0 = ((size_t)bh * SEQ + skey) * HD + schunk * 8;

    // prologue: stage tile 0 (keys 0..63) into buf 0
    gll16(&Khi[sg0], &kb[0][0][wave * 16][0]);
    gll16(&Khi[sg0 + 8 * HD], &kb[0][0][wave * 16 + 8][0]);
    gll16(&Klo[sg0], &kb[0][1][wave * 16][0]);
    gll16(&Klo[sg0 + 8 * HD], &kb[0][1][wave * 16 + 8][0]);
    __syncthreads();

    f4 cacc[4] = {};
    for (int h2 = 0; h2 < 32; ++h2) {
        const int cur = h2 & 1;
        const int kc = h2 * 64;

        // BOTH halves' V loads first (register path, L2-resident) so the PV
        // vmcnt wait retires them without draining the stage loads issued next
        // (vmcnt retires in issue order).
        short8 vB[2][4];
#pragma unroll
        for (int hf = 0; hf < 2; ++hf)
#pragma unroll
            for (int ns = 0; ns < 4; ++ns)
                vB[hf][ns] =
                    ld8(&Vt[((size_t)bh * HD + ns * 16 + la) * SEQ + kc + hf * 32 + qd * 8]);

        // async-stage tile h2+1 into the other buffer
        if (h2 + 1 < 32) {
            const size_t sn = sg0 + (size_t)(kc + 64) * HD;
            gll16(&Khi[sn], &kb[cur ^ 1][0][wave * 16][0]);
            gll16(&Khi[sn + 8 * HD], &kb[cur ^ 1][0][wave * 16 + 8][0]);
            gll16(&Klo[sn], &kb[cur ^ 1][1][wave * 16][0]);
            gll16(&Klo[sn + 8 * HD], &kb[cur ^ 1][1][wave * 16 + 8][0]);
        }

#pragma unroll
        for (int hf = 0; hf < 2; ++hf) {
            const int c0 = kc + hf * 32;
            // K fragments from LDS (swizzled read; bit-identical bf16 words)
            short8 kH[2][2], kL[2][2];
#pragma unroll
            for (int n2 = 0; n2 < 2; ++n2)
#pragma unroll
                for (int ks = 0; ks < 2; ++ks) {
                    int row = (hf * 2 + n2) * 16 + la;
                    int sw = ((ks * 4 + qd) ^ (la & 7)) * 8;
                    kH[n2][ks] = *(const short8*)&kb[cur][0][row][sw];
                    kL[n2][ks] = *(const short8*)&kb[cur][1][row][sw];
                }

            // QK^T, 3-pass hi/lo chain — per-element op order identical to r5/r8
            f4 s[2] = {};
            __builtin_amdgcn_s_setprio(1);
#pragma unroll
            for (int n2 = 0; n2 < 2; ++n2)
#pragma unroll
                for (int ks = 0; ks < 2; ++ks) {
                    s[n2] = mfma16(qlo[ks], kH[n2][ks], s[n2]);
                    s[n2] = mfma16(qhi[ks], kL[n2][ks], s[n2]);
                    s[n2] = mfma16(qhi[ks], kH[n2][ks], s[n2]);
                }
            __builtin_amdgcn_s_setprio(0);

            // spike -> Ps (wave-private rows)
#pragma unroll
            for (int n2 = 0; n2 < 2; ++n2)
#pragma unroll
                for (int r = 0; r < 4; ++r)
                    Ps[wave * 16 + qd * 4 + r][n2 * 16 + la] =
                        s[n2][r] > 0.f ? (ushort)0x3f80 : (ushort)0;

            // attn tile: Ps readback -> widen -> coalesced float4 nt stores
#pragma unroll
            for (int it = 0; it < 2; ++it) {
                int row = it * 8 + (lane >> 3);
                short4 p = *(const short4*)&Ps[wave * 16 + row][(lane & 7) * 4];
                f4 o;
                o.x = __uint_as_float(((unsigned)(ushort)p.x) << 16);
                o.y = __uint_as_float(((unsigned)(ushort)p.y) << 16);
                o.z = __uint_as_float(((unsigned)(ushort)p.z) << 16);
                o.w = __uint_as_float(((unsigned)(ushort)p.w) << 16);
                __builtin_nontemporal_store(
                    o, (f4*)&attn[((size_t)bh * SEQ + q0 + row) * SEQ + c0 + (lane & 7) * 4]);
            }

            // ctx += P @ V over this 32-key half
            short8 pa = *(const short8*)&Ps[wave * 16 + la][qd * 8];
            __builtin_amdgcn_s_setprio(1);
#pragma unroll
            for (int ns = 0; ns < 4; ++ns) cacc[ns] = mfma16(pa, vB[hf][ns], cacc[ns]);
            __builtin_amdgcn_s_setprio(0);
        }

        // release kb[cur] for restaging; guarantees stage of tile h2+1 landed.
        __syncthreads();
    }
#pragma unroll
    for (int ns = 0; ns < 4; ++ns)
#pragma unroll
        for (int r = 0; r < 4; ++r) {
            int qrow = q0 + qd * 4 + r;
            __builtin_nontemporal_store(rne16(cacc[ns][r]),
                                        &ctxb[((size_t)bh * SEQ + qrow) * HD + ns * 16 + la]);
        }
}

// ---------- out projection: 16-row waves, 4 blocks/CU, pipelined ----------
template <int B>
__device__ __forceinline__ void ld_o(const ushort* __restrict__ Ctx, const ushort* __restrict__ Wb,
                                     int m0, int n0, int la, int qd, int k0,
                                     short8 (&aO)[2], short8 (&wO)[2][4]) {
    {
        int m = m0 + la;
        int b = m >> 11, s = m & 2047;
        int k = k0 + qd * 8;
        int h = k >> 6, d = k & 63;
        aO[B] = ld8(&Ctx[((size_t)(b * NH + h) * SEQ + s) * HD + d]);
    }
#pragma unroll
    for (int ns = 0; ns < 4; ++ns)
        wO[B][ns] = ld8(&Wb[(size_t)(n0 + ns * 16 + la) * DIM + k0 + qd * 8]);
}

__global__ __launch_bounds__(256, 4) void proj_out(const ushort* __restrict__ Ctx,
                                                   const ushort* __restrict__ Wb,
                                                   const float* __restrict__ bias,
                                                   float* __restrict__ out) {
    const int t = threadIdx.x, wave = t >> 6, lane = t & 63;
    const int la = lane & 15, qd = lane >> 4;
    const int m0 = blockIdx.x * 64 + wave * 16;
    const int n0 = blockIdx.y * 64;

    short8 aO[2], wO[2][4];
    f4 acc[4] = {};
    ld_o<0>(Ctx, Wb, m0, n0, la, qd, 0, aO, wO);
    for (int k0 = 0; k0 < DIM; k0 += 64) {
        ld_o<1>(Ctx, Wb, m0, n0, la, qd, k0 + 32, aO, wO);
#pragma unroll
        for (int ns = 0; ns < 4; ++ns) acc[ns] = mfma16(aO[0], wO[0][ns], acc[ns]);
        ld_o<0>(Ctx, Wb, m0, n0, la, qd, (k0 + 64) & (DIM - 1), aO, wO);
#pragma unroll
        for (int ns = 0; ns < 4; ++ns) acc[ns] = mfma16(aO[1], wO[1][ns], acc[ns]);
    }
#pragma unroll
    for (int ns = 0; ns < 4; ++ns) {
        int n = n0 + ns * 16 + la;
        float bvv = bias[n];
#pragma unroll
        for (int r = 0; r < 4; ++r) {
            int m = m0 + qd * 4 + r;
            __builtin_nontemporal_store(acc[ns][r] + bvv, &out[(size_t)m * DIM + n]);
        }
    }
}

extern "C" void kernel_launch(void* const* d_in, const int* in_sizes, int n_in,
                              void* d_out, int out_size, void* d_ws, size_t ws_size,
                              hipStream_t stream) {
    const float* query = (const float*)d_in[0];
    const float* key   = (const float*)d_in[1];
    const float* value = (const float*)d_in[2];
    const float* Wq = (const float*)d_in[3];
    const float* bq = (const float*)d_in[4];
    const float* Wk = (const float*)d_in[5];
    const float* bk = (const float*)d_in[6];
    const float* Wv = (const float*)d_in[7];
    const float* bv = (const float*)d_in[8];
    const float* Wo = (const float*)d_in[9];
    const float* bo = (const float*)d_in[10];

    float* out  = (float*)d_out;
    float* attn = out + (size_t)MROWS * DIM;

    const size_t NE = (size_t)MROWS * DIM;  // 4,194,304
    const size_t WE = (size_t)DIM * DIM;    // 1,048,576
    ushort* Qhi = (ushort*)d_ws;            // 5 x NE = 40 MiB
    ushort* Qlo = Qhi + NE;
    ushort* Khi = Qlo + NE;
    ushort* Klo = Khi + NE;
    ushort* Vt  = Klo + NE;
    ushort* Wqh = Vt + NE;                  // 6 x WE = 12 MiB
    ushort* Wql = Wqh + WE;
    ushort* Wkh = Wql + WE;
    ushort* Wkl = Wkh + WE;
    ushort* Wvb = Wkl + WE;
    ushort* Wob = Wvb + WE;
    ushort* Ctx = Wqh;                      // overlays Wqh..Wkl (dead after proj_qkv)

    dim3 blk(256);
    hipLaunchKernelGGL(wconv, dim3(WE / 1024, 4), blk, 0, stream,
                       Wq, Wk, Wv, Wo, Wqh, Wql, Wkh, Wkl, Wvb, Wob);
    hipLaunchKernelGGL(proj_qkv, dim3(32, 16, 3), blk, 0, stream,
                       query, key, value, Wqh, Wql, Wkh, Wkl, Wvb, bq, bk, bv,
                       Qhi, Qlo, Khi, Klo, Vt);
    hipLaunchKernelGGL(attn_mfma, dim3(32, 32), blk, 0, stream,
                       Qhi, Qlo, Khi, Klo, Vt, attn, Ctx);
    hipLaunchKernelGGL(proj_out, dim3(64, 16), blk, 0, stream, Ctx, Wob, bo, out);
}

// Round 7
// 903.209 us; speedup vs baseline: 1.1650x; 1.1650x over previous
//
#include <hip/hip_runtime.h>

// SpikingMultiHeadAttention — B=2, S=2048, D=1024, H=16, hd=64, fp32 I/O.
// Round 10: r8 base (attn 32-key staged tiles, proj_out r8 form) + ONE change:
// proj_qkv W-operand LDS staging. W (hi+lo) staged per 64-K step via
// global_load_lds w16, pre-swizzled source + XOR-involution read (r8's
// HW-validated scheme), double-buffered, shared by all 4 waves (they share
// n0 -> 4x dedup). A stays per-wave fp32 register loads + split2.
// Numerics bit-identical to r8 (same bf16 words, same MFMA order): absmax 1.75.
// MFMA 16x16x32 bf16 layouts (HW-verified):
//   A-frag: lane holds A[m=lane&15][k=(lane>>4)*8+j], j=0..7
//   B-frag: lane holds Bt[n=lane&15][k=(lane>>4)*8+j]
//   C/D:    lane,reg r -> row m=(lane>>4)*4+r, col n=lane&15

#define SEQ 2048
#define DIM 1024
#define NH 16
#define HD 64
#define BATCH 2
#define MROWS (BATCH * SEQ)   // 4096
#define BHT (BATCH * NH)      // 32

typedef __attribute__((ext_vector_type(8))) short short8;
typedef __attribute__((ext_vector_type(4))) float f4;
typedef unsigned short ushort;

__device__ __forceinline__ f4 mfma16(short8 a, short8 b, f4 c) {
    return __builtin_amdgcn_mfma_f32_16x16x32_bf16(a, b, c, 0, 0, 0);
}
__device__ __forceinline__ ushort rne16(float x) {
    union { float f; unsigned u; } a; a.f = x;
    return (ushort)((a.u + 0x7fffu + ((a.u >> 16) & 1u)) >> 16);
}
// x ~= hi + lo: hi = truncate-to-bf16(x), lo = rne-bf16(x - hi)
__device__ __forceinline__ void split2(float x, ushort& h, ushort& l) {
    union { float f; unsigned u; } a; a.f = x;
    unsigned hu = a.u & 0xffff0000u;
    h = (ushort)(hu >> 16);
    union { unsigned u; float f; } hb; hb.u = hu;
    l = rne16(x - hb.f);
}
__device__ __forceinline__ short8 ld8(const ushort* p) { return *(const short8*)p; }

// async global->LDS, 16B per lane; LDS dest wave-uniform base, HW writes
// lane i at base + i*16. Global addr is per-lane.
__device__ __forceinline__ void gll16(const ushort* g, ushort* l) {
    __builtin_amdgcn_global_load_lds((const __attribute__((address_space(1))) void*)g,
                                     (__attribute__((address_space(3))) void*)l, 16, 0, 0);
}

// ---------- fused weight conversion: 4 jobs on grid.y ----------
__global__ __launch_bounds__(256) void wconv(const float* __restrict__ Wq,
                                             const float* __restrict__ Wk,
                                             const float* __restrict__ Wv,
                                             const float* __restrict__ Wo,
                                             ushort* __restrict__ Wqh, ushort* __restrict__ Wql,
                                             ushort* __restrict__ Wkh, ushort* __restrict__ Wkl,
                                             ushort* __restrict__ Wvb, ushort* __restrict__ Wob) {
    int i = (blockIdx.x * 256 + threadIdx.x) * 4;
    int job = blockIdx.y;
    const float* src = job == 0 ? Wq : job == 1 ? Wk : job == 2 ? Wv : Wo;
    float4 w = *(const float4*)&src[i];
    float xs[4] = {w.x, w.y, w.z, w.w};
    if (job < 2) {
        ushort h[4], l[4];
#pragma unroll
        for (int j = 0; j < 4; ++j) split2(xs[j], h[j], l[j]);
        ushort* ph = job ? Wkh : Wqh;
        ushort* pl = job ? Wkl : Wql;
        *(short4*)&ph[i] = make_short4(h[0], h[1], h[2], h[3]);
        *(short4*)&pl[i] = make_short4(l[0], l[1], l[2], l[3]);
    } else {
        ushort* po = job == 2 ? Wvb : Wob;
        *(short4*)&po[i] = make_short4(rne16(xs[0]), rne16(xs[1]), rne16(xs[2]), rne16(xs[3]));
    }
}

// ---------- fused q/k/v projection: W LDS-staged (dbuf, swizzled) ----------
// Grid (32, 16, 3). 4 waves/block share the W tile (same n0, different m0).
// LDS: wst[2][2][64][64] = 32 KiB (+ Ts 20 KiB for z==2) -> 2-3 blocks/CU.
__global__ __launch_bounds__(256, 2) void proj_qkv(
    const float* __restrict__ query, const float* __restrict__ key, const float* __restrict__ value,
    const ushort* __restrict__ Wqh, const ushort* __restrict__ Wql,
    const ushort* __restrict__ Wkh, const ushort* __restrict__ Wkl,
    const ushort* __restrict__ Wvb,
    const float* __restrict__ bq, const float* __restrict__ bk, const float* __restrict__ bv,
    ushort* __restrict__ Qhi, ushort* __restrict__ Qlo,
    ushort* __restrict__ Khi, ushort* __restrict__ Klo, ushort* __restrict__ Vt) {
    __shared__ ushort wst[2][2][64][64];  // [buf][hi/lo][row][hw], chunk-swizzled content
    __shared__ ushort Ts[4][64][40];      // z==2 transpose staging (wave-private rows)
    const int z = blockIdx.z;
    const int t = threadIdx.x, wave = t >> 6, lane = t & 63;
    const int la = lane & 15, qd = lane >> 4;
    const int m0 = blockIdx.x * 128 + wave * 32;
    const int n0 = blockIdx.y * 64;

    // staging geometry: wave w stages rows [w*16, w*16+16) of the 64-row W tile
    // in two 8-row gll16 groups. lane l -> row group+(l>>3), chunk (l&7).
    // LDS slot [row][j] holds GLOBAL chunk j^(row&7) (involution); row&7 == l>>3.
    const int srow = wave * 16 + (lane >> 3);
    const int schunk = (lane & 7) ^ (lane >> 3);
    const size_t wg0 = (size_t)(n0 + srow) * DIM + schunk * 8;

    if (z < 2) {
        const float* X = z ? key : query;
        const ushort* Wh = z ? Wkh : Wqh;
        const ushort* Wl = z ? Wkl : Wql;

        // prologue: stage k0=0 into buf 0
        gll16(&Wh[wg0], &wst[0][0][wave * 16][0]);
        gll16(&Wh[wg0 + 8 * DIM], &wst[0][0][wave * 16 + 8][0]);
        gll16(&Wl[wg0], &wst[0][1][wave * 16][0]);
        gll16(&Wl[wg0 + 8 * DIM], &wst[0][1][wave * 16 + 8][0]);
        __syncthreads();

        f4 acc[2][4] = {};
        for (int k0 = 0; k0 < DIM; k0 += 64) {
            const int cur = (k0 >> 6) & 1;
            // A loads for this k0 (both 32-k halves), fp32 register path
            float4 xA[2][2][2];  // [half][ms][2]
#pragma unroll
            for (int hf = 0; hf < 2; ++hf)
#pragma unroll
                for (int ms = 0; ms < 2; ++ms) {
                    const float* ap = &X[(size_t)(m0 + ms * 16 + la) * DIM + k0 + hf * 32 + qd * 8];
                    xA[hf][ms][0] = *(const float4*)ap;
                    xA[hf][ms][1] = *(const float4*)(ap + 4);
                }
            // async-stage k0+64 into the other buffer
            if (k0 + 64 < DIM) {
                gll16(&Wh[wg0 + k0 + 64], &wst[cur ^ 1][0][wave * 16][0]);
                gll16(&Wh[wg0 + k0 + 64 + 8 * DIM], &wst[cur ^ 1][0][wave * 16 + 8][0]);
                gll16(&Wl[wg0 + k0 + 64], &wst[cur ^ 1][1][wave * 16][0]);
                gll16(&Wl[wg0 + k0 + 64 + 8 * DIM], &wst[cur ^ 1][1][wave * 16 + 8][0]);
            }
#pragma unroll
            for (int hf = 0; hf < 2; ++hf) {
                short8 ahi[2], alo[2];
#pragma unroll
                for (int ms = 0; ms < 2; ++ms) {
                    float xs[8] = {xA[hf][ms][0].x, xA[hf][ms][0].y, xA[hf][ms][0].z,
                                   xA[hf][ms][0].w, xA[hf][ms][1].x, xA[hf][ms][1].y,
                                   xA[hf][ms][1].z, xA[hf][ms][1].w};
#pragma unroll
                    for (int j = 0; j < 8; ++j) {
                        ushort h, l;
                        split2(xs[j], h, l);
                        ahi[ms][j] = (short)h;
                        alo[ms][j] = (short)l;
                    }
                }
#pragma unroll
                for (int ns = 0; ns < 4; ++ns) {
                    int row = ns * 16 + la;
                    int sw = ((hf * 4 + qd) ^ (la & 7)) * 8;
                    short8 wHf = *(const short8*)&wst[cur][0][row][sw];
                    short8 wLf = *(const short8*)&wst[cur][1][row][sw];
#pragma unroll
                    for (int ms = 0; ms < 2; ++ms) {
                        acc[ms][ns] = mfma16(alo[ms], wHf, acc[ms][ns]);
                        acc[ms][ns] = mfma16(ahi[ms], wLf, acc[ms][ns]);
                        acc[ms][ns] = mfma16(ahi[ms], wHf, acc[ms][ns]);
                    }
                }
            }
            __syncthreads();  // release wst[cur]; stage of k0+64 has landed
        }
        const float* bias = z ? bk : bq;
        ushort* Oh = z ? Khi : Qhi;
        ushort* Ol = z ? Klo : Qlo;
#pragma unroll
        for (int ns = 0; ns < 4; ++ns) {
            int n = n0 + ns * 16 + la;
            float bvv = bias[n];
            int h = n >> 6, d = n & 63;
#pragma unroll
            for (int ms = 0; ms < 2; ++ms)
#pragma unroll
                for (int r = 0; r < 4; ++r) {
                    int m = m0 + ms * 16 + qd * 4 + r;
                    int b = m >> 11, s = m & 2047;
                    ushort hh, ll;
                    split2(acc[ms][ns][r] + bvv, hh, ll);
                    size_t o = ((size_t)(b * NH + h) * SEQ + s) * HD + d;
                    __builtin_nontemporal_store(hh, &Oh[o]);
                    __builtin_nontemporal_store(ll, &Ol[o]);
                }
        }
    } else {
        // V projection: single bf16 W, same staging (hl=0 only)
        gll16(&Wvb[wg0], &wst[0][0][wave * 16][0]);
        gll16(&Wvb[wg0 + 8 * DIM], &wst[0][0][wave * 16 + 8][0]);
        __syncthreads();

        f4 acc[2][4] = {};
        for (int k0 = 0; k0 < DIM; k0 += 64) {
            const int cur = (k0 >> 6) & 1;
            float4 xA[2][2][2];
#pragma unroll
            for (int hf = 0; hf < 2; ++hf)
#pragma unroll
                for (int ms = 0; ms < 2; ++ms) {
                    const float* ap =
                        &value[(size_t)(m0 + ms * 16 + la) * DIM + k0 + hf * 32 + qd * 8];
                    xA[hf][ms][0] = *(const float4*)ap;
                    xA[hf][ms][1] = *(const float4*)(ap + 4);
                }
            if (k0 + 64 < DIM) {
                gll16(&Wvb[wg0 + k0 + 64], &wst[cur ^ 1][0][wave * 16][0]);
                gll16(&Wvb[wg0 + k0 + 64 + 8 * DIM], &wst[cur ^ 1][0][wave * 16 + 8][0]);
            }
#pragma unroll
            for (int hf = 0; hf < 2; ++hf) {
                short8 a[2];
#pragma unroll
                for (int ms = 0; ms < 2; ++ms) {
                    float xs[8] = {xA[hf][ms][0].x, xA[hf][ms][0].y, xA[hf][ms][0].z,
                                   xA[hf][ms][0].w, xA[hf][ms][1].x, xA[hf][ms][1].y,
                                   xA[hf][ms][1].z, xA[hf][ms][1].w};
#pragma unroll
                    for (int j = 0; j < 8; ++j) a[ms][j] = (short)rne16(xs[j]);
                }
#pragma unroll
                for (int ns = 0; ns < 4; ++ns) {
                    int row = ns * 16 + la;
                    int sw = ((hf * 4 + qd) ^ (la & 7)) * 8;
                    short8 wv = *(const short8*)&wst[cur][0][row][sw];
#pragma unroll
                    for (int ms = 0; ms < 2; ++ms) acc[ms][ns] = mfma16(a[ms], wv, acc[ms][ns]);
                }
            }
            __syncthreads();
        }
#pragma unroll
        for (int ns = 0; ns < 4; ++ns) {
            float bvv = bv[n0 + ns * 16 + la];
#pragma unroll
            for (int ms = 0; ms < 2; ++ms)
#pragma unroll
                for (int r = 0; r < 4; ++r)
                    Ts[wave][ns * 16 + la][ms * 16 + qd * 4 + r] = rne16(acc[ms][ns][r] + bvv);
        }
        // same-wave LDS round-trip (lgkmcnt-ordered, wave-private region)
        int b = m0 >> 11, s0 = m0 & 2047, h = n0 >> 6;
        size_t vbase = (size_t)(b * NH + h) * HD * SEQ;
#pragma unroll
        for (int it = 0; it < 4; ++it) {
            int d = it * 16 + (lane >> 2), sc = (lane & 3) * 8;
            short8 v0 = *(const short8*)&Ts[wave][d][sc];
            __builtin_nontemporal_store(v0, (short8*)&Vt[vbase + (size_t)d * SEQ + s0 + sc]);
        }
    }
}

// ---------- fused attention: LDS-staged K (dbuf, swizzled), 32-key tiles ----
// Grid 32 (bh) x 32 (q-blocks of 64). 4 waves/block share the K tile.
// LDS: kb[2][2][32][64] = 16 KiB + Ps 5 KiB -> 4 blocks/CU. (r8 form, best)
__global__ __launch_bounds__(256, 4) void attn_mfma(
    const ushort* __restrict__ Qhi, const ushort* __restrict__ Qlo,
    const ushort* __restrict__ Khi, const ushort* __restrict__ Klo,
    const ushort* __restrict__ Vt, float* __restrict__ attn, ushort* __restrict__ ctxb) {
    __shared__ ushort kb[2][2][32][64];  // [buf][hl][key][halfword], chunk-swizzled content
    __shared__ ushort Ps[64][40];        // 4 waves x 16 wave-private rows
    const int t = threadIdx.x, wave = t >> 6, lane = t & 63;
    const int la = lane & 15, qd = lane >> 4;
    const int bh = blockIdx.x;
    const int q0 = blockIdx.y * 64 + wave * 16;

    short8 qhi[2], qlo[2];
#pragma unroll
    for (int ks = 0; ks < 2; ++ks) {
        size_t qi = ((size_t)bh * SEQ + q0 + la) * HD + ks * 32 + qd * 8;
        qhi[ks] = ld8(&Qhi[qi]);
        qlo[ks] = ld8(&Qlo[qi]);
    }

    const int skey = wave * 8 + (lane >> 3);
    const int schunk = (lane & 7) ^ (lane >> 3);
    const size_t sgbase = ((size_t)bh * SEQ + skey) * HD + schunk * 8;

    // prologue: stage tile 0 into buf 0
    gll16(&Khi[sgbase], &kb[0][0][wave * 8][0]);
    gll16(&Klo[sgbase], &kb[0][1][wave * 8][0]);
    __syncthreads();

    f4 cacc[4] = {};
    for (int h = 0; h < 64; ++h) {
        const int c0 = h * 32;
        const int cur = h & 1;

        short8 vB[4];
#pragma unroll
        for (int ns = 0; ns < 4; ++ns)
            vB[ns] = ld8(&Vt[((size_t)bh * HD + ns * 16 + la) * SEQ + c0 + qd * 8]);

        if (h + 1 < 64) {
            gll16(&Khi[sgbase + (size_t)(c0 + 32) * HD], &kb[cur ^ 1][0][wave * 8][0]);
            gll16(&Klo[sgbase + (size_t)(c0 + 32) * HD], &kb[cur ^ 1][1][wave * 8][0]);
        }

        short8 kH[2][2], kL[2][2];
#pragma unroll
        for (int n2 = 0; n2 < 2; ++n2)
#pragma unroll
            for (int ks = 0; ks < 2; ++ks) {
                int row = n2 * 16 + la;
                int sw = ((ks * 4 + qd) ^ (la & 7)) * 8;
                kH[n2][ks] = *(const short8*)&kb[cur][0][row][sw];
                kL[n2][ks] = *(const short8*)&kb[cur][1][row][sw];
            }

        f4 s[2] = {};
        __builtin_amdgcn_s_setprio(1);
#pragma unroll
        for (int n2 = 0; n2 < 2; ++n2)
#pragma unroll
            for (int ks = 0; ks < 2; ++ks) {
                s[n2] = mfma16(qlo[ks], kH[n2][ks], s[n2]);
                s[n2] = mfma16(qhi[ks], kL[n2][ks], s[n2]);
                s[n2] = mfma16(qhi[ks], kH[n2][ks], s[n2]);
            }
        __builtin_amdgcn_s_setprio(0);

#pragma unroll
        for (int n2 = 0; n2 < 2; ++n2)
#pragma unroll
            for (int r = 0; r < 4; ++r)
                Ps[wave * 16 + qd * 4 + r][n2 * 16 + la] =
                    s[n2][r] > 0.f ? (ushort)0x3f80 : (ushort)0;

#pragma unroll
        for (int it = 0; it < 2; ++it) {
            int row = it * 8 + (lane >> 3);
            short4 p = *(const short4*)&Ps[wave * 16 + row][(lane & 7) * 4];
            f4 o;
            o.x = __uint_as_float(((unsigned)(ushort)p.x) << 16);
            o.y = __uint_as_float(((unsigned)(ushort)p.y) << 16);
            o.z = __uint_as_float(((unsigned)(ushort)p.z) << 16);
            o.w = __uint_as_float(((unsigned)(ushort)p.w) << 16);
            __builtin_nontemporal_store(
                o, (f4*)&attn[((size_t)bh * SEQ + q0 + row) * SEQ + c0 + (lane & 7) * 4]);
        }

        short8 pa = *(const short8*)&Ps[wave * 16 + la][qd * 8];
        __builtin_amdgcn_s_setprio(1);
#pragma unroll
        for (int ns = 0; ns < 4; ++ns) cacc[ns] = mfma16(pa, vB[ns], cacc[ns]);
        __builtin_amdgcn_s_setprio(0);

        __syncthreads();
    }
#pragma unroll
    for (int ns = 0; ns < 4; ++ns)
#pragma unroll
        for (int r = 0; r < 4; ++r) {
            int qrow = q0 + qd * 4 + r;
            __builtin_nontemporal_store(rne16(cacc[ns][r]),
                                        &ctxb[((size_t)bh * SEQ + qrow) * HD + ns * 16 + la]);
        }
}

// ---------- out projection, pipelined (r8 form) ----------
template <int B>
__device__ __forceinline__ void ld_o(const ushort* __restrict__ Ctx, const ushort* __restrict__ Wb,
                                     int m0, int n0, int la, int qd, int k0,
                                     short8 (&aO)[2][2], short8 (&wO)[2][4]) {
#pragma unroll
    for (int ms = 0; ms < 2; ++ms) {
        int m = m0 + ms * 16 + la;
        int b = m >> 11, s = m & 2047;
        int k = k0 + qd * 8;
        int h = k >> 6, d = k & 63;
        aO[B][ms] = ld8(&Ctx[((size_t)(b * NH + h) * SEQ + s) * HD + d]);
    }
#pragma unroll
    for (int ns = 0; ns < 4; ++ns)
        wO[B][ns] = ld8(&Wb[(size_t)(n0 + ns * 16 + la) * DIM + k0 + qd * 8]);
}

__global__ __launch_bounds__(256, 2) void proj_out(const ushort* __restrict__ Ctx,
                                                   const ushort* __restrict__ Wb,
                                                   const float* __restrict__ bias,
                                                   float* __restrict__ out) {
    const int t = threadIdx.x, wave = t >> 6, lane = t & 63;
    const int la = lane & 15, qd = lane >> 4;
    const int m0 = blockIdx.x * 128 + wave * 32;
    const int n0 = blockIdx.y * 64;

    short8 aO[2][2], wO[2][4];
    f4 acc[2][4] = {};
    ld_o<0>(Ctx, Wb, m0, n0, la, qd, 0, aO, wO);
    for (int k0 = 0; k0 < DIM; k0 += 64) {
        ld_o<1>(Ctx, Wb, m0, n0, la, qd, k0 + 32, aO, wO);
#pragma unroll
        for (int ns = 0; ns < 4; ++ns)
#pragma unroll
            for (int ms = 0; ms < 2; ++ms) acc[ms][ns] = mfma16(aO[0][ms], wO[0][ns], acc[ms][ns]);
        ld_o<0>(Ctx, Wb, m0, n0, la, qd, (k0 + 64) & (DIM - 1), aO, wO);
#pragma unroll
        for (int ns = 0; ns < 4; ++ns)
#pragma unroll
            for (int ms = 0; ms < 2; ++ms) acc[ms][ns] = mfma16(aO[1][ms], wO[1][ns], acc[ms][ns]);
    }
#pragma unroll
    for (int ns = 0; ns < 4; ++ns) {
        int n = n0 + ns * 16 + la;
        float bvv = bias[n];
#pragma unroll
        for (int ms = 0; ms < 2; ++ms)
#pragma unroll
            for (int r = 0; r < 4; ++r) {
                int m = m0 + ms * 16 + qd * 4 + r;
                __builtin_nontemporal_store(acc[ms][ns][r] + bvv, &out[(size_t)m * DIM + n]);
            }
    }
}

extern "C" void kernel_launch(void* const* d_in, const int* in_sizes, int n_in,
                              void* d_out, int out_size, void* d_ws, size_t ws_size,
                              hipStream_t stream) {
    const float* query = (const float*)d_in[0];
    const float* key   = (const float*)d_in[1];
    const float* value = (const float*)d_in[2];
    const float* Wq = (const float*)d_in[3];
    const float* bq = (const float*)d_in[4];
    const float* Wk = (const float*)d_in[5];
    const float* bk = (const float*)d_in[6];
    const float* Wv = (const float*)d_in[7];
    const float* bv = (const float*)d_in[8];
    const float* Wo = (const float*)d_in[9];
    const float* bo = (const float*)d_in[10];

    float* out  = (float*)d_out;
    float* attn = out + (size_t)MROWS * DIM;

    const size_t NE = (size_t)MROWS * DIM;  // 4,194,304
    const size_t WE = (size_t)DIM * DIM;    // 1,048,576
    ushort* Qhi = (ushort*)d_ws;            // 5 x NE = 40 MiB
    ushort* Qlo = Qhi + NE;
    ushort* Khi = Qlo + NE;
    ushort* Klo = Khi + NE;
    ushort* Vt  = Klo + NE;
    ushort* Wqh = Vt + NE;                  // 6 x WE = 12 MiB
    ushort* Wql = Wqh + WE;
    ushort* Wkh = Wql + WE;
    ushort* Wkl = Wkh + WE;
    ushort* Wvb = Wkl + WE;
    ushort* Wob = Wvb + WE;
    ushort* Ctx = Wqh;                      // overlays Wqh..Wkl (dead after proj_qkv)

    dim3 blk(256);
    hipLaunchKernelGGL(wconv, dim3(WE / 1024, 4), blk, 0, stream,
                       Wq, Wk, Wv, Wo, Wqh, Wql, Wkh, Wkl, Wvb, Wob);
    hipLaunchKernelGGL(proj_qkv, dim3(32, 16, 3), blk, 0, stream,
                       query, key, value, Wqh, Wql, Wkh, Wkl, Wvb, bq, bk, bv,
                       Qhi, Qlo, Khi, Klo, Vt);
    hipLaunchKernelGGL(attn_mfma, dim3(32, 32), blk, 0, stream,
                       Qhi, Qlo, Khi, Klo, Vt, attn, Ctx);
    hipLaunchKernelGGL(proj_out, dim3(32, 16), blk, 0, stream, Ctx, Wob, bo, out);
}

// Round 8
// 881.536 us; speedup vs baseline: 1.1936x; 1.0246x over previous
//
#include <hip/hip_runtime.h>

// SpikingMultiHeadAttention — B=2, S=2048, D=1024, H=16, hd=64, fp32 I/O.
// Round 11: r10 base + ONE change: proj_out W-operand LDS staging (same
// mechanism as r10's proj_qkv staging, 2-for-2 validated): Wob tile dbuf'd
// via global_load_lds w16, pre-swizzled source + XOR-involution read, shared
// by all 4 waves (same n0 -> 4x dedup). Ctx stays register-loaded.
// Numerics bit-identical to r10 (same bf16 words, same MFMA order): absmax 1.75.
// MFMA 16x16x32 bf16 layouts (HW-verified):
//   A-frag: lane holds A[m=lane&15][k=(lane>>4)*8+j], j=0..7
//   B-frag: lane holds Bt[n=lane&15][k=(lane>>4)*8+j]
//   C/D:    lane,reg r -> row m=(lane>>4)*4+r, col n=lane&15

#define SEQ 2048
#define DIM 1024
#define NH 16
#define HD 64
#define BATCH 2
#define MROWS (BATCH * SEQ)   // 4096
#define BHT (BATCH * NH)      // 32

typedef __attribute__((ext_vector_type(8))) short short8;
typedef __attribute__((ext_vector_type(4))) float f4;
typedef unsigned short ushort;

__device__ __forceinline__ f4 mfma16(short8 a, short8 b, f4 c) {
    return __builtin_amdgcn_mfma_f32_16x16x32_bf16(a, b, c, 0, 0, 0);
}
__device__ __forceinline__ ushort rne16(float x) {
    union { float f; unsigned u; } a; a.f = x;
    return (ushort)((a.u + 0x7fffu + ((a.u >> 16) & 1u)) >> 16);
}
// x ~= hi + lo: hi = truncate-to-bf16(x), lo = rne-bf16(x - hi)
__device__ __forceinline__ void split2(float x, ushort& h, ushort& l) {
    union { float f; unsigned u; } a; a.f = x;
    unsigned hu = a.u & 0xffff0000u;
    h = (ushort)(hu >> 16);
    union { unsigned u; float f; } hb; hb.u = hu;
    l = rne16(x - hb.f);
}
__device__ __forceinline__ short8 ld8(const ushort* p) { return *(const short8*)p; }

// async global->LDS, 16B per lane; LDS dest wave-uniform base, HW writes
// lane i at base + i*16. Global addr is per-lane.
__device__ __forceinline__ void gll16(const ushort* g, ushort* l) {
    __builtin_amdgcn_global_load_lds((const __attribute__((address_space(1))) void*)g,
                                     (__attribute__((address_space(3))) void*)l, 16, 0, 0);
}

// ---------- fused weight conversion: 4 jobs on grid.y ----------
__global__ __launch_bounds__(256) void wconv(const float* __restrict__ Wq,
                                             const float* __restrict__ Wk,
                                             const float* __restrict__ Wv,
                                             const float* __restrict__ Wo,
                                             ushort* __restrict__ Wqh, ushort* __restrict__ Wql,
                                             ushort* __restrict__ Wkh, ushort* __restrict__ Wkl,
                                             ushort* __restrict__ Wvb, ushort* __restrict__ Wob) {
    int i = (blockIdx.x * 256 + threadIdx.x) * 4;
    int job = blockIdx.y;
    const float* src = job == 0 ? Wq : job == 1 ? Wk : job == 2 ? Wv : Wo;
    float4 w = *(const float4*)&src[i];
    float xs[4] = {w.x, w.y, w.z, w.w};
    if (job < 2) {
        ushort h[4], l[4];
#pragma unroll
        for (int j = 0; j < 4; ++j) split2(xs[j], h[j], l[j]);
        ushort* ph = job ? Wkh : Wqh;
        ushort* pl = job ? Wkl : Wql;
        *(short4*)&ph[i] = make_short4(h[0], h[1], h[2], h[3]);
        *(short4*)&pl[i] = make_short4(l[0], l[1], l[2], l[3]);
    } else {
        ushort* po = job == 2 ? Wvb : Wob;
        *(short4*)&po[i] = make_short4(rne16(xs[0]), rne16(xs[1]), rne16(xs[2]), rne16(xs[3]));
    }
}

// ---------- fused q/k/v projection: W LDS-staged (dbuf, swizzled) ----------
// Grid (32, 16, 3). 4 waves/block share the W tile (same n0, different m0).
// LDS: wst[2][2][64][64] = 32 KiB (+ Ts 20 KiB for z==2) -> 2-3 blocks/CU.
__global__ __launch_bounds__(256, 2) void proj_qkv(
    const float* __restrict__ query, const float* __restrict__ key, const float* __restrict__ value,
    const ushort* __restrict__ Wqh, const ushort* __restrict__ Wql,
    const ushort* __restrict__ Wkh, const ushort* __restrict__ Wkl,
    const ushort* __restrict__ Wvb,
    const float* __restrict__ bq, const float* __restrict__ bk, const float* __restrict__ bv,
    ushort* __restrict__ Qhi, ushort* __restrict__ Qlo,
    ushort* __restrict__ Khi, ushort* __restrict__ Klo, ushort* __restrict__ Vt) {
    __shared__ ushort wst[2][2][64][64];  // [buf][hi/lo][row][hw], chunk-swizzled content
    __shared__ ushort Ts[4][64][40];      // z==2 transpose staging (wave-private rows)
    const int z = blockIdx.z;
    const int t = threadIdx.x, wave = t >> 6, lane = t & 63;
    const int la = lane & 15, qd = lane >> 4;
    const int m0 = blockIdx.x * 128 + wave * 32;
    const int n0 = blockIdx.y * 64;

    // staging geometry: wave w stages rows [w*16, w*16+16) of the 64-row W tile
    // in two 8-row gll16 groups. lane l -> row group+(l>>3), chunk (l&7).
    // LDS slot [row][j] holds GLOBAL chunk j^(row&7) (involution); row&7 == l>>3.
    const int srow = wave * 16 + (lane >> 3);
    const int schunk = (lane & 7) ^ (lane >> 3);
    const size_t wg0 = (size_t)(n0 + srow) * DIM + schunk * 8;

    if (z < 2) {
        const float* X = z ? key : query;
        const ushort* Wh = z ? Wkh : Wqh;
        const ushort* Wl = z ? Wkl : Wql;

        // prologue: stage k0=0 into buf 0
        gll16(&Wh[wg0], &wst[0][0][wave * 16][0]);
        gll16(&Wh[wg0 + 8 * DIM], &wst[0][0][wave * 16 + 8][0]);
        gll16(&Wl[wg0], &wst[0][1][wave * 16][0]);
        gll16(&Wl[wg0 + 8 * DIM], &wst[0][1][wave * 16 + 8][0]);
        __syncthreads();

        f4 acc[2][4] = {};
        for (int k0 = 0; k0 < DIM; k0 += 64) {
            const int cur = (k0 >> 6) & 1;
            // A loads for this k0 (both 32-k halves), fp32 register path
            float4 xA[2][2][2];  // [half][ms][2]
#pragma unroll
            for (int hf = 0; hf < 2; ++hf)
#pragma unroll
                for (int ms = 0; ms < 2; ++ms) {
                    const float* ap = &X[(size_t)(m0 + ms * 16 + la) * DIM + k0 + hf * 32 + qd * 8];
                    xA[hf][ms][0] = *(const float4*)ap;
                    xA[hf][ms][1] = *(const float4*)(ap + 4);
                }
            // async-stage k0+64 into the other buffer
            if (k0 + 64 < DIM) {
                gll16(&Wh[wg0 + k0 + 64], &wst[cur ^ 1][0][wave * 16][0]);
                gll16(&Wh[wg0 + k0 + 64 + 8 * DIM], &wst[cur ^ 1][0][wave * 16 + 8][0]);
                gll16(&Wl[wg0 + k0 + 64], &wst[cur ^ 1][1][wave * 16][0]);
                gll16(&Wl[wg0 + k0 + 64 + 8 * DIM], &wst[cur ^ 1][1][wave * 16 + 8][0]);
            }
#pragma unroll
            for (int hf = 0; hf < 2; ++hf) {
                short8 ahi[2], alo[2];
#pragma unroll
                for (int ms = 0; ms < 2; ++ms) {
                    float xs[8] = {xA[hf][ms][0].x, xA[hf][ms][0].y, xA[hf][ms][0].z,
                                   xA[hf][ms][0].w, xA[hf][ms][1].x, xA[hf][ms][1].y,
                                   xA[hf][ms][1].z, xA[hf][ms][1].w};
#pragma unroll
                    for (int j = 0; j < 8; ++j) {
                        ushort h, l;
                        split2(xs[j], h, l);
                        ahi[ms][j] = (short)h;
                        alo[ms][j] = (short)l;
                    }
                }
#pragma unroll
                for (int ns = 0; ns < 4; ++ns) {
                    int row = ns * 16 + la;
                    int sw = ((hf * 4 + qd) ^ (la & 7)) * 8;
                    short8 wHf = *(const short8*)&wst[cur][0][row][sw];
                    short8 wLf = *(const short8*)&wst[cur][1][row][sw];
#pragma unroll
                    for (int ms = 0; ms < 2; ++ms) {
                        acc[ms][ns] = mfma16(alo[ms], wHf, acc[ms][ns]);
                        acc[ms][ns] = mfma16(ahi[ms], wLf, acc[ms][ns]);
                        acc[ms][ns] = mfma16(ahi[ms], wHf, acc[ms][ns]);
                    }
                }
            }
            __syncthreads();  // release wst[cur]; stage of k0+64 has landed
        }
        const float* bias = z ? bk : bq;
        ushort* Oh = z ? Khi : Qhi;
        ushort* Ol = z ? Klo : Qlo;
#pragma unroll
        for (int ns = 0; ns < 4; ++ns) {
            int n = n0 + ns * 16 + la;
            float bvv = bias[n];
            int h = n >> 6, d = n & 63;
#pragma unroll
            for (int ms = 0; ms < 2; ++ms)
#pragma unroll
                for (int r = 0; r < 4; ++r) {
                    int m = m0 + ms * 16 + qd * 4 + r;
                    int b = m >> 11, s = m & 2047;
                    ushort hh, ll;
                    split2(acc[ms][ns][r] + bvv, hh, ll);
                    size_t o = ((size_t)(b * NH + h) * SEQ + s) * HD + d;
                    __builtin_nontemporal_store(hh, &Oh[o]);
                    __builtin_nontemporal_store(ll, &Ol[o]);
                }
        }
    } else {
        // V projection: single bf16 W, same staging (hl=0 only)
        gll16(&Wvb[wg0], &wst[0][0][wave * 16][0]);
        gll16(&Wvb[wg0 + 8 * DIM], &wst[0][0][wave * 16 + 8][0]);
        __syncthreads();

        f4 acc[2][4] = {};
        for (int k0 = 0; k0 < DIM; k0 += 64) {
            const int cur = (k0 >> 6) & 1;
            float4 xA[2][2][2];
#pragma unroll
            for (int hf = 0; hf < 2; ++hf)
#pragma unroll
                for (int ms = 0; ms < 2; ++ms) {
                    const float* ap =
                        &value[(size_t)(m0 + ms * 16 + la) * DIM + k0 + hf * 32 + qd * 8];
                    xA[hf][ms][0] = *(const float4*)ap;
                    xA[hf][ms][1] = *(const float4*)(ap + 4);
                }
            if (k0 + 64 < DIM) {
                gll16(&Wvb[wg0 + k0 + 64], &wst[cur ^ 1][0][wave * 16][0]);
                gll16(&Wvb[wg0 + k0 + 64 + 8 * DIM], &wst[cur ^ 1][0][wave * 16 + 8][0]);
            }
#pragma unroll
            for (int hf = 0; hf < 2; ++hf) {
                short8 a[2];
#pragma unroll
                for (int ms = 0; ms < 2; ++ms) {
                    float xs[8] = {xA[hf][ms][0].x, xA[hf][ms][0].y, xA[hf][ms][0].z,
                                   xA[hf][ms][0].w, xA[hf][ms][1].x, xA[hf][ms][1].y,
                                   xA[hf][ms][1].z, xA[hf][ms][1].w};
#pragma unroll
                    for (int j = 0; j < 8; ++j) a[ms][j] = (short)rne16(xs[j]);
                }
#pragma unroll
                for (int ns = 0; ns < 4; ++ns) {
                    int row = ns * 16 + la;
                    int sw = ((hf * 4 + qd) ^ (la & 7)) * 8;
                    short8 wv = *(const short8*)&wst[cur][0][row][sw];
#pragma unroll
                    for (int ms = 0; ms < 2; ++ms) acc[ms][ns] = mfma16(a[ms], wv, acc[ms][ns]);
                }
            }
            __syncthreads();
        }
#pragma unroll
        for (int ns = 0; ns < 4; ++ns) {
            float bvv = bv[n0 + ns * 16 + la];
#pragma unroll
            for (int ms = 0; ms < 2; ++ms)
#pragma unroll
                for (int r = 0; r < 4; ++r)
                    Ts[wave][ns * 16 + la][ms * 16 + qd * 4 + r] = rne16(acc[ms][ns][r] + bvv);
        }
        // same-wave LDS round-trip (lgkmcnt-ordered, wave-private region)
        int b = m0 >> 11, s0 = m0 & 2047, h = n0 >> 6;
        size_t vbase = (size_t)(b * NH + h) * HD * SEQ;
#pragma unroll
        for (int it = 0; it < 4; ++it) {
            int d = it * 16 + (lane >> 2), sc = (lane & 3) * 8;
            short8 v0 = *(const short8*)&Ts[wave][d][sc];
            __builtin_nontemporal_store(v0, (short8*)&Vt[vbase + (size_t)d * SEQ + s0 + sc]);
        }
    }
}

// ---------- fused attention: LDS-staged K (dbuf, swizzled), 32-key tiles ----
// Grid 32 (bh) x 32 (q-blocks of 64). 4 waves/block share the K tile.
// LDS: kb[2][2][32][64] = 16 KiB + Ps 5 KiB -> 4 blocks/CU. (r8 form, best)
__global__ __launch_bounds__(256, 4) void attn_mfma(
    const ushort* __restrict__ Qhi, const ushort* __restrict__ Qlo,
    const ushort* __restrict__ Khi, const ushort* __restrict__ Klo,
    const ushort* __restrict__ Vt, float* __restrict__ attn, ushort* __restrict__ ctxb) {
    __shared__ ushort kb[2][2][32][64];  // [buf][hl][key][halfword], chunk-swizzled content
    __shared__ ushort Ps[64][40];        // 4 waves x 16 wave-private rows
    const int t = threadIdx.x, wave = t >> 6, lane = t & 63;
    const int la = lane & 15, qd = lane >> 4;
    const int bh = blockIdx.x;
    const int q0 = blockIdx.y * 64 + wave * 16;

    short8 qhi[2], qlo[2];
#pragma unroll
    for (int ks = 0; ks < 2; ++ks) {
        size_t qi = ((size_t)bh * SEQ + q0 + la) * HD + ks * 32 + qd * 8;
        qhi[ks] = ld8(&Qhi[qi]);
        qlo[ks] = ld8(&Qlo[qi]);
    }

    const int skey = wave * 8 + (lane >> 3);
    const int schunk = (lane & 7) ^ (lane >> 3);
    const size_t sgbase = ((size_t)bh * SEQ + skey) * HD + schunk * 8;

    // prologue: stage tile 0 into buf 0
    gll16(&Khi[sgbase], &kb[0][0][wave * 8][0]);
    gll16(&Klo[sgbase], &kb[0][1][wave * 8][0]);
    __syncthreads();

    f4 cacc[4] = {};
    for (int h = 0; h < 64; ++h) {
        const int c0 = h * 32;
        const int cur = h & 1;

        short8 vB[4];
#pragma unroll
        for (int ns = 0; ns < 4; ++ns)
            vB[ns] = ld8(&Vt[((size_t)bh * HD + ns * 16 + la) * SEQ + c0 + qd * 8]);

        if (h + 1 < 64) {
            gll16(&Khi[sgbase + (size_t)(c0 + 32) * HD], &kb[cur ^ 1][0][wave * 8][0]);
            gll16(&Klo[sgbase + (size_t)(c0 + 32) * HD], &kb[cur ^ 1][1][wave * 8][0]);
        }

        short8 kH[2][2], kL[2][2];
#pragma unroll
        for (int n2 = 0; n2 < 2; ++n2)
#pragma unroll
            for (int ks = 0; ks < 2; ++ks) {
                int row = n2 * 16 + la;
                int sw = ((ks * 4 + qd) ^ (la & 7)) * 8;
                kH[n2][ks] = *(const short8*)&kb[cur][0][row][sw];
                kL[n2][ks] = *(const short8*)&kb[cur][1][row][sw];
            }

        f4 s[2] = {};
        __builtin_amdgcn_s_setprio(1);
#pragma unroll
        for (int n2 = 0; n2 < 2; ++n2)
#pragma unroll
            for (int ks = 0; ks < 2; ++ks) {
                s[n2] = mfma16(qlo[ks], kH[n2][ks], s[n2]);
                s[n2] = mfma16(qhi[ks], kL[n2][ks], s[n2]);
                s[n2] = mfma16(qhi[ks], kH[n2][ks], s[n2]);
            }
        __builtin_amdgcn_s_setprio(0);

#pragma unroll
        for (int n2 = 0; n2 < 2; ++n2)
#pragma unroll
            for (int r = 0; r < 4; ++r)
                Ps[wave * 16 + qd * 4 + r][n2 * 16 + la] =
                    s[n2][r] > 0.f ? (ushort)0x3f80 : (ushort)0;

#pragma unroll
        for (int it = 0; it < 2; ++it) {
            int row = it * 8 + (lane >> 3);
            short4 p = *(const short4*)&Ps[wave * 16 + row][(lane & 7) * 4];
            f4 o;
            o.x = __uint_as_float(((unsigned)(ushort)p.x) << 16);
            o.y = __uint_as_float(((unsigned)(ushort)p.y) << 16);
            o.z = __uint_as_float(((unsigned)(ushort)p.z) << 16);
            o.w = __uint_as_float(((unsigned)(ushort)p.w) << 16);
            __builtin_nontemporal_store(
                o, (f4*)&attn[((size_t)bh * SEQ + q0 + row) * SEQ + c0 + (lane & 7) * 4]);
        }

        short8 pa = *(const short8*)&Ps[wave * 16 + la][qd * 8];
        __builtin_amdgcn_s_setprio(1);
#pragma unroll
        for (int ns = 0; ns < 4; ++ns) cacc[ns] = mfma16(pa, vB[ns], cacc[ns]);
        __builtin_amdgcn_s_setprio(0);

        __syncthreads();
    }
#pragma unroll
    for (int ns = 0; ns < 4; ++ns)
#pragma unroll
        for (int r = 0; r < 4; ++r) {
            int qrow = q0 + qd * 4 + r;
            __builtin_nontemporal_store(rne16(cacc[ns][r]),
                                        &ctxb[((size_t)bh * SEQ + qrow) * HD + ns * 16 + la]);
        }
}

// ---------- out projection: W LDS-staged (dbuf, swizzled) ----------
// Grid (32, 16). 4 waves/block share the W tile (same n0).
// LDS: wst[2][64][64] = 16 KiB -> well within 2 blocks/CU budget.
__global__ __launch_bounds__(256, 2) void proj_out(const ushort* __restrict__ Ctx,
                                                   const ushort* __restrict__ Wb,
                                                   const float* __restrict__ bias,
                                                   float* __restrict__ out) {
    __shared__ ushort wst[2][64][64];  // [buf][row][hw], chunk-swizzled content
    const int t = threadIdx.x, wave = t >> 6, lane = t & 63;
    const int la = lane & 15, qd = lane >> 4;
    const int m0 = blockIdx.x * 128 + wave * 32;
    const int n0 = blockIdx.y * 64;

    const int srow = wave * 16 + (lane >> 3);
    const int schunk = (lane & 7) ^ (lane >> 3);
    const size_t wg0 = (size_t)(n0 + srow) * DIM + schunk * 8;

    // prologue: stage k0=0 into buf 0
    gll16(&Wb[wg0], &wst[0][wave * 16][0]);
    gll16(&Wb[wg0 + 8 * DIM], &wst[0][wave * 16 + 8][0]);
    __syncthreads();

    f4 acc[2][4] = {};
    for (int k0 = 0; k0 < DIM; k0 += 64) {
        const int cur = (k0 >> 6) & 1;
        const int hsel = k0 >> 6;  // head index = k/64 (constant within the tile)
        // Ctx loads (per-wave rows, register path)
        short8 aO[2][2];  // [half][ms]
#pragma unroll
        for (int hf = 0; hf < 2; ++hf)
#pragma unroll
            for (int ms = 0; ms < 2; ++ms) {
                int m = m0 + ms * 16 + la;
                int b = m >> 11, s = m & 2047;
                aO[hf][ms] =
                    ld8(&Ctx[((size_t)(b * NH + hsel) * SEQ + s) * HD + hf * 32 + qd * 8]);
            }
        // async-stage k0+64 into the other buffer
        if (k0 + 64 < DIM) {
            gll16(&Wb[wg0 + k0 + 64], &wst[cur ^ 1][wave * 16][0]);
            gll16(&Wb[wg0 + k0 + 64 + 8 * DIM], &wst[cur ^ 1][wave * 16 + 8][0]);
        }
#pragma unroll
        for (int hf = 0; hf < 2; ++hf)
#pragma unroll
            for (int ns = 0; ns < 4; ++ns) {
                int row = ns * 16 + la;
                int sw = ((hf * 4 + qd) ^ (la & 7)) * 8;
                short8 wv = *(const short8*)&wst[cur][row][sw];
#pragma unroll
                for (int ms = 0; ms < 2; ++ms) acc[ms][ns] = mfma16(aO[hf][ms], wv, acc[ms][ns]);
            }
        __syncthreads();  // release wst[cur]; stage of k0+64 has landed
    }
#pragma unroll
    for (int ns = 0; ns < 4; ++ns) {
        int n = n0 + ns * 16 + la;
        float bvv = bias[n];
#pragma unroll
        for (int ms = 0; ms < 2; ++ms)
#pragma unroll
            for (int r = 0; r < 4; ++r) {
                int m = m0 + ms * 16 + qd * 4 + r;
                __builtin_nontemporal_store(acc[ms][ns][r] + bvv, &out[(size_t)m * DIM + n]);
            }
    }
}

extern "C" void kernel_launch(void* const* d_in, const int* in_sizes, int n_in,
                              void* d_out, int out_size, void* d_ws, size_t ws_size,
                              hipStream_t stream) {
    const float* query = (const float*)d_in[0];
    const float* key   = (const float*)d_in[1];
    const float* value = (const float*)d_in[2];
    const float* Wq = (const float*)d_in[3];
    const float* bq = (const float*)d_in[4];
    const float* Wk = (const float*)d_in[5];
    const float* bk = (const float*)d_in[6];
    const float* Wv = (const float*)d_in[7];
    const float* bv = (const float*)d_in[8];
    const float* Wo = (const float*)d_in[9];
    const float* bo = (const float*)d_in[10];

    float* out  = (float*)d_out;
    float* attn = out + (size_t)MROWS * DIM;

    const size_t NE = (size_t)MROWS * DIM;  // 4,194,304
    const size_t WE = (size_t)DIM * DIM;    // 1,048,576
    ushort* Qhi = (ushort*)d_ws;            // 5 x NE = 40 MiB
    ushort* Qlo = Qhi + NE;
    ushort* Khi = Qlo + NE;
    ushort* Klo = Khi + NE;
    ushort* Vt  = Klo + NE;
    ushort* Wqh = Vt + NE;                  // 6 x WE = 12 MiB
    ushort* Wql = Wqh + WE;
    ushort* Wkh = Wql + WE;
    ushort* Wkl = Wkh + WE;
    ushort* Wvb = Wkl + WE;
    ushort* Wob = Wvb + WE;
    ushort* Ctx = Wqh;                      // overlays Wqh..Wkl (dead after proj_qkv)

    dim3 blk(256);
    hipLaunchKernelGGL(wconv, dim3(WE / 1024, 4), blk, 0, stream,
                       Wq, Wk, Wv, Wo, Wqh, Wql, Wkh, Wkl, Wvb, Wob);
    hipLaunchKernelGGL(proj_qkv, dim3(32, 16, 3), blk, 0, stream,
                       query, key, value, Wqh, Wql, Wkh, Wkl, Wvb, bq, bk, bv,
                       Qhi, Qlo, Khi, Klo, Vt);
    hipLaunchKernelGGL(attn_mfma, dim3(32, 32), blk, 0, stream,
                       Qhi, Qlo, Khi, Klo, Vt, attn, Ctx);
    hipLaunchKernelGGL(proj_out, dim3(32, 16), blk, 0, stream, Ctx, Wob, bo, out);
}